// Round 1
// baseline (571.527 us; speedup 1.0000x reference)
//
#include <hip/hip_runtime.h>
#include <hip/hip_bf16.h>

// ---------------------------------------------------------------------------
// AfmoE MoE: routing (sigmoid top-8) + 16 routed SwiGLU experts + shared
// expert, treated uniformly as 17 experts via gather lists.
// GEMMs: bf16 MFMA 16x16x32, C = A*B^T, both operands K-contiguous.
// ---------------------------------------------------------------------------

typedef __attribute__((ext_vector_type(8))) short bf16x8;
typedef __attribute__((ext_vector_type(4))) float f32x4;

#define NTOK 1024   // B*S
#define DD   1024   // hidden
#define II   1024   // intermediate (same for shared)
#define NE   16     // routed experts
#define NEXP 17     // + shared expert as index 16
#define KSEL 8
#define RSCALE 2.826f

// GEMM tiling
#define BM 128
#define BN 64
#define BK 32
#define LDA 40      // LDS row stride (elems), +8 pad -> 2-way bank conflicts only

// workspace layout (bytes)
#define OFF_XBF   0ull                               // ushort[NTOK*DD]      2 MiB
#define OFF_H     (2ull*1024*1024)                   // ushort[NEXP*NTOK*II] 34 MiB
#define OFF_LIST  (OFF_H + 34ull*1024*1024)          // int[NEXP*NTOK]
#define OFF_SCALE (OFF_LIST + 4ull*NEXP*NTOK)        // float[NEXP*NTOK]
#define OFF_CNT   (OFF_SCALE + 4ull*NEXP*NTOK)       // int[NEXP]

__device__ __forceinline__ unsigned short f2bf(float f) {
    union { __hip_bfloat16 h; unsigned short u; } c;
    c.h = __float2bfloat16(f);
    return c.u;
}

// --- convert x to bf16; init shared-expert list/scale/count -----------------
__global__ __launch_bounds__(256) void prep_kernel(
    const float* __restrict__ x, unsigned short* __restrict__ xbf,
    int* __restrict__ list, float* __restrict__ scalebuf, int* __restrict__ count)
{
    int idx = blockIdx.x * 256 + threadIdx.x;        // 1024 blocks -> 262144
    float4 v = ((const float4*)x)[idx];
    ((ushort4*)xbf)[idx] = make_ushort4(f2bf(v.x), f2bf(v.y), f2bf(v.z), f2bf(v.w));
    if (idx < NTOK) { list[NE * NTOK + idx] = idx; scalebuf[NE * NTOK + idx] = 1.0f; }
    if (idx == 0) count[NE] = NTOK;
}

// --- routing: one wave per token -------------------------------------------
__global__ __launch_bounds__(64) void routing_kernel(
    const float* __restrict__ x, const float* __restrict__ gw,
    const float* __restrict__ bias, int* __restrict__ count,
    int* __restrict__ list, float* __restrict__ scalebuf)
{
    int t = blockIdx.x, lane = threadIdx.x;
    float acc[NE];
#pragma unroll
    for (int e = 0; e < NE; e++) acc[e] = 0.f;
    const float* xr = x + (size_t)t * DD;
    for (int i = 0; i < DD / 64; i++) {
        float xv = xr[lane + 64 * i];
#pragma unroll
        for (int e = 0; e < NE; e++) acc[e] += xv * gw[e * DD + lane + 64 * i];
    }
#pragma unroll
    for (int e = 0; e < NE; e++) {
        float v = acc[e];
        for (int off = 32; off > 0; off >>= 1) v += __shfl_xor(v, off, 64);
        acc[e] = v;
    }
    if (lane == 0) {
        float sc[NE], sel[NE];
#pragma unroll
        for (int e = 0; e < NE; e++) {
            sc[e] = 1.f / (1.f + expf(-acc[e]));
            sel[e] = sc[e] + bias[e];
        }
        bool used[NE] = {};
        int inds[KSEL];
        float ssum = 0.f;
        for (int k = 0; k < KSEL; k++) {        // top-8, ties -> lowest index
            float best = -1e30f; int bi = 0;
            for (int e = 0; e < NE; e++)
                if (!used[e] && sel[e] > best) { best = sel[e]; bi = e; }
            used[bi] = true; inds[k] = bi; ssum += sc[bi];
        }
        float inv = RSCALE / ssum;
        for (int k = 0; k < KSEL; k++) {
            int e = inds[k];
            int pos = atomicAdd(&count[e], 1);
            list[e * NTOK + pos] = t;
            scalebuf[e * NTOK + pos] = sc[e] * inv;
        }
    }
}

// --- fused gate+up GEMM: h = silu(Xg Wg^T) * (Xg Wu^T) * route_w -----------
__global__ __launch_bounds__(256) void gateup_kernel(
    const unsigned short* __restrict__ xbf,
    const float* __restrict__ wg, const float* __restrict__ wu,
    const float* __restrict__ sgw, const float* __restrict__ suw,
    const int* __restrict__ count, const int* __restrict__ list,
    const float* __restrict__ scalebuf, unsigned short* __restrict__ hbuf)
{
    int e = blockIdx.z;
    int cnt = count[e];
    int m0 = blockIdx.x * BM;
    if (m0 >= cnt) return;
    int n0 = blockIdx.y * BN;
    const float* Bg = (e < NE) ? wg + (size_t)e * II * DD : sgw;
    const float* Bu = (e < NE) ? wu + (size_t)e * II * DD : suw;

    __shared__ __align__(16) unsigned short As[BM * LDA];
    __shared__ __align__(16) unsigned short Bgs[BN * LDA];
    __shared__ __align__(16) unsigned short Bus[BN * LDA];
    __shared__ int rowtok[BM];

    int tid = threadIdx.x;
    if (tid < BM) {
        int gr = m0 + tid;
        rowtok[tid] = (gr < cnt) ? list[e * NTOK + gr] : -1;
    }
    __syncthreads();

    int lane = tid & 63, wave = tid >> 6;
    int wm = wave >> 1, wn = wave & 1;
    int row16 = lane & 15, quad = lane >> 4;

    f32x4 accG[4][2], accU[4][2];
#pragma unroll
    for (int mi = 0; mi < 4; mi++)
#pragma unroll
        for (int ni = 0; ni < 2; ni++) {
            accG[mi][ni] = (f32x4){0.f, 0.f, 0.f, 0.f};
            accU[mi][ni] = (f32x4){0.f, 0.f, 0.f, 0.f};
        }

    for (int k0 = 0; k0 < DD; k0 += BK) {
        // stage A: 128x32 bf16, gathered token rows
#pragma unroll
        for (int i = 0; i < 2; i++) {
            int c = tid + 256 * i;
            int row = c >> 2, kc = (c & 3) * 8;
            int tok = rowtok[row];
            uint4 v = (tok >= 0) ? *(const uint4*)(xbf + (size_t)tok * DD + k0 + kc)
                                 : make_uint4(0u, 0u, 0u, 0u);
            *(uint4*)(As + row * LDA + kc) = v;
        }
        // stage Bg/Bu: 64x32 fp32 -> bf16
#pragma unroll
        for (int i = 0; i < 2; i++) {
            int c = tid + 256 * i;
            int row = c >> 3, f = (c & 7) * 4;
            float4 vg = *(const float4*)(Bg + (size_t)(n0 + row) * DD + k0 + f);
            float4 vu = *(const float4*)(Bu + (size_t)(n0 + row) * DD + k0 + f);
            *(ushort4*)(Bgs + row * LDA + f) = make_ushort4(f2bf(vg.x), f2bf(vg.y), f2bf(vg.z), f2bf(vg.w));
            *(ushort4*)(Bus + row * LDA + f) = make_ushort4(f2bf(vu.x), f2bf(vu.y), f2bf(vu.z), f2bf(vu.w));
        }
        __syncthreads();

        bf16x8 af[4], bg[2], bu[2];
#pragma unroll
        for (int mi = 0; mi < 4; mi++)
            af[mi] = *(const bf16x8*)(As + (wm * 64 + mi * 16 + row16) * LDA + quad * 8);
#pragma unroll
        for (int ni = 0; ni < 2; ni++) {
            bg[ni] = *(const bf16x8*)(Bgs + (wn * 32 + ni * 16 + row16) * LDA + quad * 8);
            bu[ni] = *(const bf16x8*)(Bus + (wn * 32 + ni * 16 + row16) * LDA + quad * 8);
        }
#pragma unroll
        for (int mi = 0; mi < 4; mi++)
#pragma unroll
            for (int ni = 0; ni < 2; ni++) {
                accG[mi][ni] = __builtin_amdgcn_mfma_f32_16x16x32_bf16(af[mi], bg[ni], accG[mi][ni], 0, 0, 0);
                accU[mi][ni] = __builtin_amdgcn_mfma_f32_16x16x32_bf16(af[mi], bu[ni], accU[mi][ni], 0, 0, 0);
            }
        __syncthreads();
    }

    // epilogue: silu(g)*u * route_scale -> bf16 h_buf
#pragma unroll
    for (int mi = 0; mi < 4; mi++) {
        int mbase = wm * 64 + mi * 16 + quad * 4;
#pragma unroll
        for (int r = 0; r < 4; r++) {
            int gr = m0 + mbase + r;
            if (gr >= cnt) continue;
            float rs = scalebuf[e * NTOK + gr];
            size_t rowoff = ((size_t)e * NTOK + gr) * II + n0;
#pragma unroll
            for (int ni = 0; ni < 2; ni++) {
                int n = wn * 32 + ni * 16 + row16;
                float g = accG[mi][ni][r], u = accU[mi][ni][r];
                float h = g / (1.f + __expf(-g)) * u * rs;
                hbuf[rowoff + n] = f2bf(h);
            }
        }
    }
}

// --- down GEMM: y[tok] += h Wd^T (scatter via atomics) ---------------------
__global__ __launch_bounds__(256) void down_kernel(
    const unsigned short* __restrict__ hbuf,
    const float* __restrict__ wd, const float* __restrict__ sdw,
    const int* __restrict__ count, const int* __restrict__ list,
    float* __restrict__ y)
{
    int e = blockIdx.z;
    int cnt = count[e];
    int m0 = blockIdx.x * BM;
    if (m0 >= cnt) return;
    int n0 = blockIdx.y * BN;
    const float* Bp = (e < NE) ? wd + (size_t)e * DD * II : sdw;

    __shared__ __align__(16) unsigned short As[BM * LDA];
    __shared__ __align__(16) unsigned short Bs[BN * LDA];

    int tid = threadIdx.x;
    int lane = tid & 63, wave = tid >> 6;
    int wm = wave >> 1, wn = wave & 1;
    int row16 = lane & 15, quad = lane >> 4;

    f32x4 acc[4][2];
#pragma unroll
    for (int mi = 0; mi < 4; mi++)
#pragma unroll
        for (int ni = 0; ni < 2; ni++) acc[mi][ni] = (f32x4){0.f, 0.f, 0.f, 0.f};

    const unsigned short* Abase = hbuf + ((size_t)e * NTOK + m0) * II;

    for (int k0 = 0; k0 < II; k0 += BK) {
#pragma unroll
        for (int i = 0; i < 2; i++) {
            int c = tid + 256 * i;
            int row = c >> 2, kc = (c & 3) * 8;
            uint4 v = (m0 + row < cnt) ? *(const uint4*)(Abase + (size_t)row * II + k0 + kc)
                                       : make_uint4(0u, 0u, 0u, 0u);
            *(uint4*)(As + row * LDA + kc) = v;
        }
#pragma unroll
        for (int i = 0; i < 2; i++) {
            int c = tid + 256 * i;
            int row = c >> 3, f = (c & 7) * 4;
            float4 v = *(const float4*)(Bp + (size_t)(n0 + row) * II + k0 + f);
            *(ushort4*)(Bs + row * LDA + f) = make_ushort4(f2bf(v.x), f2bf(v.y), f2bf(v.z), f2bf(v.w));
        }
        __syncthreads();

        bf16x8 af[4], bf[2];
#pragma unroll
        for (int mi = 0; mi < 4; mi++)
            af[mi] = *(const bf16x8*)(As + (wm * 64 + mi * 16 + row16) * LDA + quad * 8);
#pragma unroll
        for (int ni = 0; ni < 2; ni++)
            bf[ni] = *(const bf16x8*)(Bs + (wn * 32 + ni * 16 + row16) * LDA + quad * 8);
#pragma unroll
        for (int mi = 0; mi < 4; mi++)
#pragma unroll
            for (int ni = 0; ni < 2; ni++)
                acc[mi][ni] = __builtin_amdgcn_mfma_f32_16x16x32_bf16(af[mi], bf[ni], acc[mi][ni], 0, 0, 0);
        __syncthreads();
    }

    // epilogue: scatter-add into y (route weight already folded into h)
#pragma unroll
    for (int mi = 0; mi < 4; mi++) {
        int mbase = wm * 64 + mi * 16 + quad * 4;
#pragma unroll
        for (int r = 0; r < 4; r++) {
            int gr = m0 + mbase + r;
            if (gr >= cnt) continue;
            int t = list[e * NTOK + gr];
#pragma unroll
            for (int ni = 0; ni < 2; ni++) {
                int n = wn * 32 + ni * 16 + row16;
                unsafeAtomicAdd(&y[(size_t)t * DD + n0 + n], acc[mi][ni][r]);
            }
        }
    }
}

extern "C" void kernel_launch(void* const* d_in, const int* in_sizes, int n_in,
                              void* d_out, int out_size, void* d_ws, size_t ws_size,
                              hipStream_t stream)
{
    const float* x    = (const float*)d_in[0];
    const float* gw   = (const float*)d_in[1];
    const float* bias = (const float*)d_in[2];
    const float* wg   = (const float*)d_in[3];
    const float* wu   = (const float*)d_in[4];
    const float* wd   = (const float*)d_in[5];
    const float* sgw  = (const float*)d_in[6];
    const float* suw  = (const float*)d_in[7];
    const float* sdw  = (const float*)d_in[8];
    float* y = (float*)d_out;

    char* ws = (char*)d_ws;
    unsigned short* xbf  = (unsigned short*)(ws + OFF_XBF);
    unsigned short* hbuf = (unsigned short*)(ws + OFF_H);
    int*   list     = (int*)(ws + OFF_LIST);
    float* scalebuf = (float*)(ws + OFF_SCALE);
    int*   count    = (int*)(ws + OFF_CNT);

    hipMemsetAsync(d_out, 0, (size_t)NTOK * DD * sizeof(float), stream);
    hipMemsetAsync(count, 0, NEXP * sizeof(int), stream);

    prep_kernel<<<dim3(NTOK * DD / 4 / 256), 256, 0, stream>>>(x, xbf, list, scalebuf, count);
    routing_kernel<<<dim3(NTOK), 64, 0, stream>>>(x, gw, bias, count, list, scalebuf);
    gateup_kernel<<<dim3(NTOK / BM, II / BN, NEXP), 256, 0, stream>>>(
        xbf, wg, wu, sgw, suw, count, list, scalebuf, hbuf);
    down_kernel<<<dim3(NTOK / BM, DD / BN, NEXP), 256, 0, stream>>>(
        hbuf, wd, sdw, count, list, y);
}

// Round 2
// 538.511 us; speedup vs baseline: 1.0613x; 1.0613x over previous
//
#include <hip/hip_runtime.h>
#include <hip/hip_bf16.h>

// ---------------------------------------------------------------------------
// AfmoE MoE: routing (sigmoid top-8) + 16 routed SwiGLU experts + shared
// expert as expert #16 via gather lists.
// Round 1: bf16 weight materialization + m97-style async GEMMs
// (global_load_lds staging, unpadded 64B LDS rows, 2-barrier K-loop).
// ---------------------------------------------------------------------------

typedef __attribute__((ext_vector_type(8))) short bf16x8;
typedef __attribute__((ext_vector_type(4))) float f32x4;

#define NTOK 1024   // B*S
#define DD   1024   // hidden
#define II   1024   // intermediate (same for shared)
#define NE   16     // routed experts
#define NEXP 17     // + shared expert as index 16
#define KSEL 8
#define RSCALE 2.826f

// GEMM tiling
#define BM 128
#define BN 64
#define BK 32
#define LDA 40      // fallback-path LDS stride

// workspace layout (bytes)
#define MB (1024ull*1024ull)
#define OFF_XBF   0ull                         // ushort[NTOK*DD]          2 MiB
#define OFF_H     (2ull*MB)                    // ushort[NEXP*NTOK*II]    34 MiB
#define OFF_WG    (36ull*MB)                   // ushort[NEXP*II*DD]      34 MiB
#define OFF_WU    (70ull*MB)                   // ushort[NEXP*II*DD]      34 MiB
#define OFF_WD    (104ull*MB)                  // ushort[NEXP*DD*II]      34 MiB
#define OFF_LIST  (138ull*MB)                  // int[NEXP*NTOK]
#define OFF_SCALE (OFF_LIST + 4ull*NEXP*NTOK)  // float[NEXP*NTOK]
#define OFF_CNT   (OFF_SCALE + 4ull*NEXP*NTOK) // int[NEXP]
#define WS_NEED   (OFF_CNT + 4096ull)

__device__ __forceinline__ unsigned short f2bf(float f) {
    union { __hip_bfloat16 h; unsigned short u; } c;
    c.h = __float2bfloat16(f);
    return c.u;
}

__device__ __forceinline__ void gl2lds16(const unsigned short* g, unsigned short* l) {
    __builtin_amdgcn_global_load_lds(
        (const __attribute__((address_space(1))) void*)g,
        (__attribute__((address_space(3))) void*)l, 16, 0, 0);
}

// --- convert x to bf16; init shared-expert list/scale/count -----------------
__global__ __launch_bounds__(256) void prep_kernel(
    const float* __restrict__ x, unsigned short* __restrict__ xbf,
    int* __restrict__ list, float* __restrict__ scalebuf, int* __restrict__ count)
{
    int idx = blockIdx.x * 256 + threadIdx.x;
    float4 v = ((const float4*)x)[idx];
    ((ushort4*)xbf)[idx] = make_ushort4(f2bf(v.x), f2bf(v.y), f2bf(v.z), f2bf(v.w));
    if (idx < NTOK) { list[NE * NTOK + idx] = idx; scalebuf[NE * NTOK + idx] = 1.0f; }
    if (idx == 0) count[NE] = NTOK;
}

// --- convert all expert weights fp32 -> bf16 pools -------------------------
__global__ __launch_bounds__(256) void wconv_kernel(
    const float* __restrict__ wg, const float* __restrict__ wu, const float* __restrict__ wd,
    const float* __restrict__ sgw, const float* __restrict__ suw, const float* __restrict__ sdw,
    unsigned short* __restrict__ wgb, unsigned short* __restrict__ wub,
    unsigned short* __restrict__ wdb)
{
    size_t i4 = (size_t)blockIdx.x * 256 + threadIdx.x;     // float4 index in pool
    const size_t ROUTED4 = (size_t)NE * II * DD / 4;        // 4194304
    int p = blockIdx.y;
    const float* rsrc = (p == 0) ? wg : (p == 1) ? wu : wd;
    const float* ssrc = (p == 0) ? sgw : (p == 1) ? suw : sdw;
    unsigned short* dst = (p == 0) ? wgb : (p == 1) ? wub : wdb;
    const float* src = (i4 < ROUTED4) ? rsrc + 4 * i4 : ssrc + 4 * (i4 - ROUTED4);
    float4 v = *(const float4*)src;
    ((ushort4*)dst)[i4] = make_ushort4(f2bf(v.x), f2bf(v.y), f2bf(v.z), f2bf(v.w));
}

// --- routing: one wave per token -------------------------------------------
__global__ __launch_bounds__(64) void routing_kernel(
    const float* __restrict__ x, const float* __restrict__ gw,
    const float* __restrict__ bias, int* __restrict__ count,
    int* __restrict__ list, float* __restrict__ scalebuf)
{
    int t = blockIdx.x, lane = threadIdx.x;
    float acc[NE];
#pragma unroll
    for (int e = 0; e < NE; e++) acc[e] = 0.f;
    const float* xr = x + (size_t)t * DD;
    for (int i = 0; i < DD / 64; i++) {
        float xv = xr[lane + 64 * i];
#pragma unroll
        for (int e = 0; e < NE; e++) acc[e] += xv * gw[e * DD + lane + 64 * i];
    }
#pragma unroll
    for (int e = 0; e < NE; e++) {
        float v = acc[e];
        for (int off = 32; off > 0; off >>= 1) v += __shfl_xor(v, off, 64);
        acc[e] = v;
    }
    if (lane == 0) {
        float sc[NE], sel[NE];
#pragma unroll
        for (int e = 0; e < NE; e++) {
            sc[e] = 1.f / (1.f + expf(-acc[e]));
            sel[e] = sc[e] + bias[e];
        }
        bool used[NE] = {};
        int inds[KSEL];
        float ssum = 0.f;
        for (int k = 0; k < KSEL; k++) {
            float best = -1e30f; int bi = 0;
            for (int e = 0; e < NE; e++)
                if (!used[e] && sel[e] > best) { best = sel[e]; bi = e; }
            used[bi] = true; inds[k] = bi; ssum += sc[bi];
        }
        float inv = RSCALE / ssum;
        for (int k = 0; k < KSEL; k++) {
            int e = inds[k];
            int pos = atomicAdd(&count[e], 1);
            list[e * NTOK + pos] = t;
            scalebuf[e * NTOK + pos] = sc[e] * inv;
        }
    }
}

// --- async fused gate+up GEMM ----------------------------------------------
// h = silu(Xg Wg^T) * (Xg Wu^T) * route_w, all operands bf16, LDS rows 64B.
__global__ __launch_bounds__(256) void gateup_kernel(
    const unsigned short* __restrict__ xbf,
    const unsigned short* __restrict__ wgb, const unsigned short* __restrict__ wub,
    const int* __restrict__ count, const int* __restrict__ list,
    const float* __restrict__ scalebuf, unsigned short* __restrict__ hbuf)
{
    int e = blockIdx.z;
    int cnt = count[e];
    int m0 = blockIdx.x * BM;
    if (m0 >= cnt) return;
    int n0 = blockIdx.y * BN;
    const unsigned short* Bg = wgb + (size_t)e * II * DD;
    const unsigned short* Bu = wub + (size_t)e * II * DD;

    __shared__ __align__(16) unsigned short As[BM * 32];   // 8 KB
    __shared__ __align__(16) unsigned short Bgs[BN * 32];  // 4 KB
    __shared__ __align__(16) unsigned short Bus[BN * 32];  // 4 KB
    __shared__ int rowtok[BM];

    int tid = threadIdx.x;
    if (tid < BM) {
        int gr = m0 + tid;
        rowtok[tid] = list[e * NTOK + ((gr < cnt) ? gr : 0)];
    }
    __syncthreads();

    int lane = tid & 63, wave = tid >> 6;
    int wm = wave >> 1, wn = wave & 1;
    int row16 = lane & 15, quad = lane >> 4;

    // staging geometry (all chunk = 16B = 8 ushorts)
    int cA0 = (wave * 2 + 0) * 64 + lane;          // [0,512)
    int cA1 = (wave * 2 + 1) * 64 + lane;
    int tokA0 = rowtok[cA0 >> 2], tokA1 = rowtok[cA1 >> 2];
    int subA0 = (cA0 & 3) * 8, subA1 = (cA1 & 3) * 8;
    unsigned short* ldsA0 = As + (size_t)(wave * 2 + 0) * 512;  // wave-uniform base
    unsigned short* ldsA1 = As + (size_t)(wave * 2 + 1) * 512;
    int cB = wave * 64 + lane;                      // [0,256)
    int rB = n0 + (cB >> 2);
    int subB = (cB & 3) * 8;
    unsigned short* ldsBg = Bgs + (size_t)wave * 512;
    unsigned short* ldsBu = Bus + (size_t)wave * 512;
    const unsigned short* gA0 = xbf + (size_t)tokA0 * DD + subA0;
    const unsigned short* gA1 = xbf + (size_t)tokA1 * DD + subA1;
    const unsigned short* gBg = Bg + (size_t)rB * DD + subB;
    const unsigned short* gBu = Bu + (size_t)rB * DD + subB;

    f32x4 accG[4][2], accU[4][2];
#pragma unroll
    for (int mi = 0; mi < 4; mi++)
#pragma unroll
        for (int ni = 0; ni < 2; ni++) {
            accG[mi][ni] = (f32x4){0.f, 0.f, 0.f, 0.f};
            accU[mi][ni] = (f32x4){0.f, 0.f, 0.f, 0.f};
        }

    for (int k0 = 0; k0 < DD; k0 += BK) {
        gl2lds16(gA0 + k0, ldsA0);
        gl2lds16(gA1 + k0, ldsA1);
        gl2lds16(gBg + k0, ldsBg);
        gl2lds16(gBu + k0, ldsBu);
        __syncthreads();

        bf16x8 af[4], bg[2], bu[2];
#pragma unroll
        for (int mi = 0; mi < 4; mi++)
            af[mi] = *(const bf16x8*)(As + (wm * 64 + mi * 16 + row16) * 32 + quad * 8);
#pragma unroll
        for (int ni = 0; ni < 2; ni++) {
            bg[ni] = *(const bf16x8*)(Bgs + (wn * 32 + ni * 16 + row16) * 32 + quad * 8);
            bu[ni] = *(const bf16x8*)(Bus + (wn * 32 + ni * 16 + row16) * 32 + quad * 8);
        }
#pragma unroll
        for (int mi = 0; mi < 4; mi++)
#pragma unroll
            for (int ni = 0; ni < 2; ni++) {
                accG[mi][ni] = __builtin_amdgcn_mfma_f32_16x16x32_bf16(af[mi], bg[ni], accG[mi][ni], 0, 0, 0);
                accU[mi][ni] = __builtin_amdgcn_mfma_f32_16x16x32_bf16(af[mi], bu[ni], accU[mi][ni], 0, 0, 0);
            }
        __syncthreads();
    }

#pragma unroll
    for (int mi = 0; mi < 4; mi++) {
        int mbase = wm * 64 + mi * 16 + quad * 4;
#pragma unroll
        for (int r = 0; r < 4; r++) {
            int gr = m0 + mbase + r;
            if (gr >= cnt) continue;
            float rs = scalebuf[e * NTOK + gr];
            size_t rowoff = ((size_t)e * NTOK + gr) * II + n0;
#pragma unroll
            for (int ni = 0; ni < 2; ni++) {
                int n = wn * 32 + ni * 16 + row16;
                float g = accG[mi][ni][r], u = accU[mi][ni][r];
                float h = g / (1.f + __expf(-g)) * u * rs;
                hbuf[rowoff + n] = f2bf(h);
            }
        }
    }
}

// --- async down GEMM: y[tok] += h Wd^T (atomic scatter) --------------------
__global__ __launch_bounds__(256) void down_kernel(
    const unsigned short* __restrict__ hbuf,
    const unsigned short* __restrict__ wdb,
    const int* __restrict__ count, const int* __restrict__ list,
    float* __restrict__ y)
{
    int e = blockIdx.z;
    int cnt = count[e];
    int m0 = blockIdx.x * BM;
    if (m0 >= cnt) return;
    int n0 = blockIdx.y * BN;
    const unsigned short* Bp = wdb + (size_t)e * DD * II;
    const unsigned short* Abase = hbuf + ((size_t)e * NTOK + m0) * II;

    __shared__ __align__(16) unsigned short As[BM * 32];
    __shared__ __align__(16) unsigned short Bs[BN * 32];

    int tid = threadIdx.x;
    int lane = tid & 63, wave = tid >> 6;
    int wm = wave >> 1, wn = wave & 1;
    int row16 = lane & 15, quad = lane >> 4;

    int cA0 = (wave * 2 + 0) * 64 + lane;
    int cA1 = (wave * 2 + 1) * 64 + lane;
    // rows >= cnt read stale hbuf (tiny 0xAA-pattern bf16 values); results discarded.
    const unsigned short* gA0 = Abase + (size_t)(cA0 >> 2) * II + (cA0 & 3) * 8;
    const unsigned short* gA1 = Abase + (size_t)(cA1 >> 2) * II + (cA1 & 3) * 8;
    unsigned short* ldsA0 = As + (size_t)(wave * 2 + 0) * 512;
    unsigned short* ldsA1 = As + (size_t)(wave * 2 + 1) * 512;
    int cB = wave * 64 + lane;
    const unsigned short* gB = Bp + (size_t)(n0 + (cB >> 2)) * II + (cB & 3) * 8;
    unsigned short* ldsB = Bs + (size_t)wave * 512;

    f32x4 acc[4][2];
#pragma unroll
    for (int mi = 0; mi < 4; mi++)
#pragma unroll
        for (int ni = 0; ni < 2; ni++) acc[mi][ni] = (f32x4){0.f, 0.f, 0.f, 0.f};

    for (int k0 = 0; k0 < II; k0 += BK) {
        gl2lds16(gA0 + k0, ldsA0);
        gl2lds16(gA1 + k0, ldsA1);
        gl2lds16(gB + k0, ldsB);
        __syncthreads();

        bf16x8 af[4], bf[2];
#pragma unroll
        for (int mi = 0; mi < 4; mi++)
            af[mi] = *(const bf16x8*)(As + (wm * 64 + mi * 16 + row16) * 32 + quad * 8);
#pragma unroll
        for (int ni = 0; ni < 2; ni++)
            bf[ni] = *(const bf16x8*)(Bs + (wn * 32 + ni * 16 + row16) * 32 + quad * 8);
#pragma unroll
        for (int mi = 0; mi < 4; mi++)
#pragma unroll
            for (int ni = 0; ni < 2; ni++)
                acc[mi][ni] = __builtin_amdgcn_mfma_f32_16x16x32_bf16(af[mi], bf[ni], acc[mi][ni], 0, 0, 0);
        __syncthreads();
    }

#pragma unroll
    for (int mi = 0; mi < 4; mi++) {
        int mbase = wm * 64 + mi * 16 + quad * 4;
#pragma unroll
        for (int r = 0; r < 4; r++) {
            int gr = m0 + mbase + r;
            if (gr >= cnt) continue;
            int t = list[e * NTOK + gr];
#pragma unroll
            for (int ni = 0; ni < 2; ni++) {
                int n = wn * 32 + ni * 16 + row16;
                unsafeAtomicAdd(&y[(size_t)t * DD + n0 + n], acc[mi][ni][r]);
            }
        }
    }
}

// ======================= fallback path (round-0 kernels) ====================
__global__ __launch_bounds__(256) void gateup_fb(
    const unsigned short* __restrict__ xbf,
    const float* __restrict__ wg, const float* __restrict__ wu,
    const float* __restrict__ sgw, const float* __restrict__ suw,
    const int* __restrict__ count, const int* __restrict__ list,
    const float* __restrict__ scalebuf, unsigned short* __restrict__ hbuf)
{
    int e = blockIdx.z;
    int cnt = count[e];
    int m0 = blockIdx.x * BM;
    if (m0 >= cnt) return;
    int n0 = blockIdx.y * BN;
    const float* Bg = (e < NE) ? wg + (size_t)e * II * DD : sgw;
    const float* Bu = (e < NE) ? wu + (size_t)e * II * DD : suw;

    __shared__ __align__(16) unsigned short As[BM * LDA];
    __shared__ __align__(16) unsigned short Bgs[BN * LDA];
    __shared__ __align__(16) unsigned short Bus[BN * LDA];
    __shared__ int rowtok[BM];

    int tid = threadIdx.x;
    if (tid < BM) {
        int gr = m0 + tid;
        rowtok[tid] = (gr < cnt) ? list[e * NTOK + gr] : -1;
    }
    __syncthreads();

    int lane = tid & 63, wave = tid >> 6;
    int wm = wave >> 1, wn = wave & 1;
    int row16 = lane & 15, quad = lane >> 4;

    f32x4 accG[4][2], accU[4][2];
#pragma unroll
    for (int mi = 0; mi < 4; mi++)
#pragma unroll
        for (int ni = 0; ni < 2; ni++) {
            accG[mi][ni] = (f32x4){0.f, 0.f, 0.f, 0.f};
            accU[mi][ni] = (f32x4){0.f, 0.f, 0.f, 0.f};
        }

    for (int k0 = 0; k0 < DD; k0 += BK) {
#pragma unroll
        for (int i = 0; i < 2; i++) {
            int c = tid + 256 * i;
            int row = c >> 2, kc = (c & 3) * 8;
            int tok = rowtok[row];
            uint4 v = (tok >= 0) ? *(const uint4*)(xbf + (size_t)tok * DD + k0 + kc)
                                 : make_uint4(0u, 0u, 0u, 0u);
            *(uint4*)(As + row * LDA + kc) = v;
        }
#pragma unroll
        for (int i = 0; i < 2; i++) {
            int c = tid + 256 * i;
            int row = c >> 3, f = (c & 7) * 4;
            float4 vg = *(const float4*)(Bg + (size_t)(n0 + row) * DD + k0 + f);
            float4 vu = *(const float4*)(Bu + (size_t)(n0 + row) * DD + k0 + f);
            *(ushort4*)(Bgs + row * LDA + f) = make_ushort4(f2bf(vg.x), f2bf(vg.y), f2bf(vg.z), f2bf(vg.w));
            *(ushort4*)(Bus + row * LDA + f) = make_ushort4(f2bf(vu.x), f2bf(vu.y), f2bf(vu.z), f2bf(vu.w));
        }
        __syncthreads();

        bf16x8 af[4], bg[2], bu[2];
#pragma unroll
        for (int mi = 0; mi < 4; mi++)
            af[mi] = *(const bf16x8*)(As + (wm * 64 + mi * 16 + row16) * LDA + quad * 8);
#pragma unroll
        for (int ni = 0; ni < 2; ni++) {
            bg[ni] = *(const bf16x8*)(Bgs + (wn * 32 + ni * 16 + row16) * LDA + quad * 8);
            bu[ni] = *(const bf16x8*)(Bus + (wn * 32 + ni * 16 + row16) * LDA + quad * 8);
        }
#pragma unroll
        for (int mi = 0; mi < 4; mi++)
#pragma unroll
            for (int ni = 0; ni < 2; ni++) {
                accG[mi][ni] = __builtin_amdgcn_mfma_f32_16x16x32_bf16(af[mi], bg[ni], accG[mi][ni], 0, 0, 0);
                accU[mi][ni] = __builtin_amdgcn_mfma_f32_16x16x32_bf16(af[mi], bu[ni], accU[mi][ni], 0, 0, 0);
            }
        __syncthreads();
    }

#pragma unroll
    for (int mi = 0; mi < 4; mi++) {
        int mbase = wm * 64 + mi * 16 + quad * 4;
#pragma unroll
        for (int r = 0; r < 4; r++) {
            int gr = m0 + mbase + r;
            if (gr >= cnt) continue;
            float rs = scalebuf[e * NTOK + gr];
            size_t rowoff = ((size_t)e * NTOK + gr) * II + n0;
#pragma unroll
            for (int ni = 0; ni < 2; ni++) {
                int n = wn * 32 + ni * 16 + row16;
                float g = accG[mi][ni][r], u = accU[mi][ni][r];
                float h = g / (1.f + __expf(-g)) * u * rs;
                hbuf[rowoff + n] = f2bf(h);
            }
        }
    }
}

__global__ __launch_bounds__(256) void down_fb(
    const unsigned short* __restrict__ hbuf,
    const float* __restrict__ wd, const float* __restrict__ sdw,
    const int* __restrict__ count, const int* __restrict__ list,
    float* __restrict__ y)
{
    int e = blockIdx.z;
    int cnt = count[e];
    int m0 = blockIdx.x * BM;
    if (m0 >= cnt) return;
    int n0 = blockIdx.y * BN;
    const float* Bp = (e < NE) ? wd + (size_t)e * DD * II : sdw;

    __shared__ __align__(16) unsigned short As[BM * LDA];
    __shared__ __align__(16) unsigned short Bs[BN * LDA];

    int tid = threadIdx.x;
    int lane = tid & 63, wave = tid >> 6;
    int wm = wave >> 1, wn = wave & 1;
    int row16 = lane & 15, quad = lane >> 4;

    f32x4 acc[4][2];
#pragma unroll
    for (int mi = 0; mi < 4; mi++)
#pragma unroll
        for (int ni = 0; ni < 2; ni++) acc[mi][ni] = (f32x4){0.f, 0.f, 0.f, 0.f};

    const unsigned short* Abase = hbuf + ((size_t)e * NTOK + m0) * II;

    for (int k0 = 0; k0 < II; k0 += BK) {
#pragma unroll
        for (int i = 0; i < 2; i++) {
            int c = tid + 256 * i;
            int row = c >> 2, kc = (c & 3) * 8;
            uint4 v = (m0 + row < cnt) ? *(const uint4*)(Abase + (size_t)row * II + k0 + kc)
                                       : make_uint4(0u, 0u, 0u, 0u);
            *(uint4*)(As + row * LDA + kc) = v;
        }
#pragma unroll
        for (int i = 0; i < 2; i++) {
            int c = tid + 256 * i;
            int row = c >> 3, f = (c & 7) * 4;
            float4 v = *(const float4*)(Bp + (size_t)(n0 + row) * II + k0 + f);
            *(ushort4*)(Bs + row * LDA + f) = make_ushort4(f2bf(v.x), f2bf(v.y), f2bf(v.z), f2bf(v.w));
        }
        __syncthreads();

        bf16x8 af[4], bf[2];
#pragma unroll
        for (int mi = 0; mi < 4; mi++)
            af[mi] = *(const bf16x8*)(As + (wm * 64 + mi * 16 + row16) * LDA + quad * 8);
#pragma unroll
        for (int ni = 0; ni < 2; ni++)
            bf[ni] = *(const bf16x8*)(Bs + (wn * 32 + ni * 16 + row16) * LDA + quad * 8);
#pragma unroll
        for (int mi = 0; mi < 4; mi++)
#pragma unroll
            for (int ni = 0; ni < 2; ni++)
                acc[mi][ni] = __builtin_amdgcn_mfma_f32_16x16x32_bf16(af[mi], bf[ni], acc[mi][ni], 0, 0, 0);
        __syncthreads();
    }

#pragma unroll
    for (int mi = 0; mi < 4; mi++) {
        int mbase = wm * 64 + mi * 16 + quad * 4;
#pragma unroll
        for (int r = 0; r < 4; r++) {
            int gr = m0 + mbase + r;
            if (gr >= cnt) continue;
            int t = list[e * NTOK + gr];
#pragma unroll
            for (int ni = 0; ni < 2; ni++) {
                int n = wn * 32 + ni * 16 + row16;
                unsafeAtomicAdd(&y[(size_t)t * DD + n0 + n], acc[mi][ni][r]);
            }
        }
    }
}

extern "C" void kernel_launch(void* const* d_in, const int* in_sizes, int n_in,
                              void* d_out, int out_size, void* d_ws, size_t ws_size,
                              hipStream_t stream)
{
    const float* x    = (const float*)d_in[0];
    const float* gw   = (const float*)d_in[1];
    const float* bias = (const float*)d_in[2];
    const float* wg   = (const float*)d_in[3];
    const float* wu   = (const float*)d_in[4];
    const float* wd   = (const float*)d_in[5];
    const float* sgw  = (const float*)d_in[6];
    const float* suw  = (const float*)d_in[7];
    const float* sdw  = (const float*)d_in[8];
    float* y = (float*)d_out;

    char* ws = (char*)d_ws;
    unsigned short* xbf  = (unsigned short*)(ws + OFF_XBF);
    unsigned short* hbuf = (unsigned short*)(ws + OFF_H);
    unsigned short* wgb  = (unsigned short*)(ws + OFF_WG);
    unsigned short* wub  = (unsigned short*)(ws + OFF_WU);
    unsigned short* wdb  = (unsigned short*)(ws + OFF_WD);
    int*   list     = (int*)(ws + OFF_LIST);
    float* scalebuf = (float*)(ws + OFF_SCALE);
    int*   count    = (int*)(ws + OFF_CNT);

    bool big = (ws_size >= WS_NEED);
    if (!big) {
        // small-ws fallback layout (round-0)
        list     = (int*)(ws + 36ull * MB);
        scalebuf = (float*)(ws + 36ull * MB + 4ull * NEXP * NTOK);
        count    = (int*)(ws + 36ull * MB + 8ull * NEXP * NTOK);
    }

    hipMemsetAsync(d_out, 0, (size_t)NTOK * DD * sizeof(float), stream);
    hipMemsetAsync(count, 0, NEXP * sizeof(int), stream);

    prep_kernel<<<dim3(NTOK * DD / 4 / 256), 256, 0, stream>>>(x, xbf, list, scalebuf, count);
    routing_kernel<<<dim3(NTOK), 64, 0, stream>>>(x, gw, bias, count, list, scalebuf);

    if (big) {
        wconv_kernel<<<dim3((unsigned)((size_t)NEXP * II * DD / 4 / 256), 3), 256, 0, stream>>>(
            wg, wu, wd, sgw, suw, sdw, wgb, wub, wdb);
        gateup_kernel<<<dim3(NTOK / BM, II / BN, NEXP), 256, 0, stream>>>(
            xbf, wgb, wub, count, list, scalebuf, hbuf);
        down_kernel<<<dim3(NTOK / BM, DD / BN, NEXP), 256, 0, stream>>>(
            hbuf, wdb, count, list, y);
    } else {
        gateup_fb<<<dim3(NTOK / BM, II / BN, NEXP), 256, 0, stream>>>(
            xbf, wg, wu, sgw, suw, count, list, scalebuf, hbuf);
        down_fb<<<dim3(NTOK / BM, DD / BN, NEXP), 256, 0, stream>>>(
            hbuf, wd, sdw, count, list, y);
    }
}